// Round 1
// baseline (590.258 us; speedup 1.0000x reference)
//
#include <hip/hip_runtime.h>
#include <hip/hip_bf16.h>

// GraphSAGE 3-layer forward. fp32 throughout.
// Pipeline per call:
//   1. build CSR by dst (deg histogram -> block scan -> fill)
//   2. per layer: aggregate (mean of h[src] per dst, 1 wave/node) -> msum
//                 GEMM: out = h@Ws + msum@Wn + b (+relu)

#define THREADS 256

__global__ void k_count(const int* __restrict__ dst, int* __restrict__ deg, int E) {
    int e = blockIdx.x * blockDim.x + threadIdx.x;
    if (e < E) atomicAdd(&deg[dst[e]], 1);
}

__global__ void k_scan_block(const int* __restrict__ deg, int* __restrict__ off,
                             int* __restrict__ bsum, int n) {
    __shared__ int s[256];
    int t = threadIdx.x;
    int base = blockIdx.x * 1024 + t * 4;
    int v[4];
#pragma unroll
    for (int i = 0; i < 4; i++) v[i] = (base + i < n) ? deg[base + i] : 0;
    int sum = v[0] + v[1] + v[2] + v[3];
    int val = sum;
    s[t] = val;
    __syncthreads();
    for (int o = 1; o < 256; o <<= 1) {
        int x = (t >= o) ? s[t - o] : 0;
        __syncthreads();
        val += x;
        s[t] = val;
        __syncthreads();
    }
    int run = val - sum;  // exclusive prefix of this thread's chunk
#pragma unroll
    for (int i = 0; i < 4; i++) {
        if (base + i < n) off[base + i] = run;
        run += v[i];
    }
    if (t == 255) bsum[blockIdx.x] = val;
}

__global__ void k_scan_bsum(int* __restrict__ bsum, int nb) {
    if (threadIdx.x == 0 && blockIdx.x == 0) {
        int acc = 0;
        for (int i = 0; i < nb; i++) {
            int v = bsum[i];
            bsum[i] = acc;
            acc += v;
        }
    }
}

__global__ void k_scan_add(int* __restrict__ off, const int* __restrict__ bsum, int n) {
    int t = threadIdx.x;
    int base = blockIdx.x * 1024 + t * 4;
    int add = bsum[blockIdx.x];
#pragma unroll
    for (int i = 0; i < 4; i++)
        if (base + i < n) off[base + i] += add;
}

__global__ void k_fill(const int* __restrict__ src, const int* __restrict__ dst,
                       const int* __restrict__ off, int* __restrict__ cur,
                       int* __restrict__ eidx, int E) {
    int e = blockIdx.x * blockDim.x + threadIdx.x;
    if (e < E) {
        int d = dst[e];
        int p = atomicAdd(&cur[d], 1);
        eidx[off[d] + p] = src[e];
    }
}

__global__ void k_invdeg(const int* __restrict__ deg, float* __restrict__ inv, int n) {
    int i = blockIdx.x * blockDim.x + threadIdx.x;
    if (i < n) {
        int d = deg[i];
        inv[i] = 1.0f / (float)(d > 1 ? d : 1);
    }
}

// one wave (64 lanes) per node; lane handles 2 consecutive floats (float2)
__global__ void k_aggregate(const float* __restrict__ h_in, const int* __restrict__ eidx,
                            const int* __restrict__ off, const int* __restrict__ deg,
                            const float* __restrict__ inv, float* __restrict__ msum, int n) {
    int node = blockIdx.x * 4 + (threadIdx.x >> 6);
    int lane = threadIdx.x & 63;
    if (node >= n) return;
    int cnt = deg[node];
    int base = off[node];
    float2 acc = make_float2(0.f, 0.f);
    const float2* h2 = (const float2*)h_in;
    for (int j = 0; j < cnt; j++) {
        int s = eidx[base + j];
        float2 v = h2[(size_t)s * 64 + lane];
        acc.x += v.x;
        acc.y += v.y;
    }
    float iv = inv[node];
    float2 outv = make_float2(acc.x * iv, acc.y * iv);
    ((float2*)msum)[(size_t)node * 64 + lane] = outv;
}

// out[n, o] = sum_k h[n,k]*Ws[k,o] + hn[n,k]*Wn[k,o] + b[o]  (+relu)
// tile: 64 nodes x fout (<=128). 256 threads: o4 = t&31 (4 outs), ng = t>>5 (8 node-groups)
__global__ __launch_bounds__(256) void k_gemm(const float* __restrict__ h_in,
                                              const float* __restrict__ hn_in,
                                              const float* __restrict__ Ws,
                                              const float* __restrict__ Wn,
                                              const float* __restrict__ bias,
                                              float* __restrict__ out, int n, int fout,
                                              int relu) {
    __shared__ float hs[64 * 32];
    __shared__ float hh[64 * 32];
    __shared__ float wsl[32 * 128];
    __shared__ float wnl[32 * 128];

    int t = threadIdx.x;
    int nt0 = blockIdx.x * 64;
    int o4 = t & 31;   // output quad index: outputs o4*4 .. o4*4+3
    int ng = t >> 5;   // node group 0..7 -> nodes ng + 8*i

    float4 acc[8];
#pragma unroll
    for (int i = 0; i < 8; i++) acc[i] = make_float4(0.f, 0.f, 0.f, 0.f);

    for (int kk = 0; kk < 128; kk += 32) {
        __syncthreads();
        // stage h tiles: 64 nodes x 32 k  (512 float4s, 2 per thread)
#pragma unroll
        for (int i = 0; i < 2; i++) {
            int g = t + 256 * i;  // 0..511
            int row = g >> 3;
            int c4 = g & 7;
            int gn = nt0 + row;
            float4 v = make_float4(0.f, 0.f, 0.f, 0.f);
            float4 v2 = make_float4(0.f, 0.f, 0.f, 0.f);
            if (gn < n) {
                v = *(const float4*)&h_in[(size_t)gn * 128 + kk + c4 * 4];
                v2 = *(const float4*)&hn_in[(size_t)gn * 128 + kk + c4 * 4];
            }
            *(float4*)&hs[row * 32 + c4 * 4] = v;
            *(float4*)&hh[row * 32 + c4 * 4] = v2;
        }
        // stage W tiles: 32 k x fout (padded to 128 cols)
        if (fout == 128) {
#pragma unroll
            for (int i = 0; i < 4; i++) {
                int g = t + 256 * i;  // 0..1023 float4s
                int kr = g >> 5;
                int c4 = g & 31;
                *(float4*)&wsl[kr * 128 + c4 * 4] =
                    *(const float4*)&Ws[(size_t)(kk + kr) * 128 + c4 * 4];
                *(float4*)&wnl[kr * 128 + c4 * 4] =
                    *(const float4*)&Wn[(size_t)(kk + kr) * 128 + c4 * 4];
            }
        } else {
#pragma unroll
            for (int i = 0; i < 16; i++) {
                int idx = t + 256 * i;  // 0..4095
                int kr = idx >> 7;
                int c = idx & 127;
                float vs = 0.f, vn = 0.f;
                if (c < fout) {
                    vs = Ws[(size_t)(kk + kr) * fout + c];
                    vn = Wn[(size_t)(kk + kr) * fout + c];
                }
                wsl[kr * 128 + c] = vs;
                wnl[kr * 128 + c] = vn;
            }
        }
        __syncthreads();

        for (int k4 = 0; k4 < 32; k4 += 4) {
            float4 wsv[4], wnv[4];
#pragma unroll
            for (int q = 0; q < 4; q++) {
                wsv[q] = *(float4*)&wsl[(k4 + q) * 128 + o4 * 4];
                wnv[q] = *(float4*)&wnl[(k4 + q) * 128 + o4 * 4];
            }
#pragma unroll
            for (int i = 0; i < 8; i++) {
                float4 hv4 = *(float4*)&hs[(ng + 8 * i) * 32 + k4];
                float4 hn4 = *(float4*)&hh[(ng + 8 * i) * 32 + k4];
                float hq[4] = {hv4.x, hv4.y, hv4.z, hv4.w};
                float nq[4] = {hn4.x, hn4.y, hn4.z, hn4.w};
                float4 a = acc[i];
#pragma unroll
                for (int q = 0; q < 4; q++) {
                    a.x += hq[q] * wsv[q].x + nq[q] * wnv[q].x;
                    a.y += hq[q] * wsv[q].y + nq[q] * wnv[q].y;
                    a.z += hq[q] * wsv[q].z + nq[q] * wnv[q].z;
                    a.w += hq[q] * wsv[q].w + nq[q] * wnv[q].w;
                }
                acc[i] = a;
            }
        }
    }

    // epilogue
    float bj[4];
#pragma unroll
    for (int j = 0; j < 4; j++) {
        int o = o4 * 4 + j;
        bj[j] = (o < fout) ? bias[o] : 0.f;
    }
#pragma unroll
    for (int i = 0; i < 8; i++) {
        int gn = nt0 + ng + 8 * i;
        if (gn >= n) continue;
        float v[4] = {acc[i].x + bj[0], acc[i].y + bj[1], acc[i].z + bj[2], acc[i].w + bj[3]};
        if (relu) {
#pragma unroll
            for (int j = 0; j < 4; j++) v[j] = v[j] > 0.f ? v[j] : 0.f;
        }
        if (fout == 128) {
            *(float4*)&out[(size_t)gn * 128 + o4 * 4] = make_float4(v[0], v[1], v[2], v[3]);
        } else {
#pragma unroll
            for (int j = 0; j < 4; j++) {
                int o = o4 * 4 + j;
                if (o < fout) out[(size_t)gn * fout + o] = v[j];
            }
        }
    }
}

extern "C" void kernel_launch(void* const* d_in, const int* in_sizes, int n_in,
                              void* d_out, int out_size, void* d_ws, size_t ws_size,
                              hipStream_t stream) {
    const float* x = (const float*)d_in[0];
    const int* src = (const int*)d_in[1];
    const int* dst = (const int*)d_in[2];
    const float* Ws0 = (const float*)d_in[3];
    const float* Wn0 = (const float*)d_in[4];
    const float* b0 = (const float*)d_in[5];
    const float* Ws1 = (const float*)d_in[6];
    const float* Wn1 = (const float*)d_in[7];
    const float* b1 = (const float*)d_in[8];
    const float* Ws2 = (const float*)d_in[9];
    const float* Wn2 = (const float*)d_in[10];
    const float* b2 = (const float*)d_in[11];
    float* out = (float*)d_out;

    const int N = in_sizes[0] / 128;
    const int E = in_sizes[1];
    const int H = 128;
    const int C = 47;

    // workspace layout
    float* wsf = (float*)d_ws;
    size_t p = 0;
    float* msum = wsf + p; p += (size_t)N * H;
    float* h0 = wsf + p;   p += (size_t)N * H;
    float* h1 = wsf + p;   p += (size_t)N * H;
    float* inv = wsf + p;  p += N;
    int* ib = (int*)(wsf + p);
    int* deg = ib;
    int* off = ib + N;
    int* cur = ib + 2 * N;
    int* eidx = ib + 3 * N;
    int* bsum = ib + 3 * N + E;

    const int nbE = (E + THREADS - 1) / THREADS;
    const int nbScan = (N + 1023) / 1024;
    const int nbN = (N + THREADS - 1) / THREADS;
    const int nbAgg = (N + 3) / 4;
    const int nbGemm = (N + 63) / 64;

    hipMemsetAsync(deg, 0, (size_t)N * sizeof(int), stream);
    hipMemsetAsync(cur, 0, (size_t)N * sizeof(int), stream);

    k_count<<<nbE, THREADS, 0, stream>>>(dst, deg, E);
    k_scan_block<<<nbScan, 256, 0, stream>>>(deg, off, bsum, N);
    k_scan_bsum<<<1, 64, 0, stream>>>(bsum, nbScan);
    k_scan_add<<<nbScan, 256, 0, stream>>>(off, bsum, N);
    k_fill<<<nbE, THREADS, 0, stream>>>(src, dst, off, cur, eidx, E);
    k_invdeg<<<nbN, THREADS, 0, stream>>>(deg, inv, N);

    // layer 0: x -> h0
    k_aggregate<<<nbAgg, 256, 0, stream>>>(x, eidx, off, deg, inv, msum, N);
    k_gemm<<<nbGemm, 256, 0, stream>>>(x, msum, Ws0, Wn0, b0, h0, N, 128, 1);
    // layer 1: h0 -> h1
    k_aggregate<<<nbAgg, 256, 0, stream>>>(h0, eidx, off, deg, inv, msum, N);
    k_gemm<<<nbGemm, 256, 0, stream>>>(h0, msum, Ws1, Wn1, b1, h1, N, 128, 1);
    // layer 2: h1 -> out (C=47, no relu)
    k_aggregate<<<nbAgg, 256, 0, stream>>>(h1, eidx, off, deg, inv, msum, N);
    k_gemm<<<nbGemm, 256, 0, stream>>>(h1, msum, Ws2, Wn2, b2, out, N, C, 0);
}

// Round 2
// 461.722 us; speedup vs baseline: 1.2784x; 1.2784x over previous
//
#include <hip/hip_runtime.h>
#include <hip/hip_bf16.h>

// GraphSAGE 3-layer forward.
// CSR build (int) -> per layer: aggregate (fp32 gather-mean, emits bf16 hi/lo
// planes) -> MFMA GEMM (bf16x3 split == fp32-quality) fused self+neigh (K=256).

#define THREADS 256

typedef unsigned short u16;
typedef __attribute__((ext_vector_type(8))) short bf16x8;
typedef __attribute__((ext_vector_type(4))) float f32x4;

__device__ inline u16 f2bf(float f) {
    union { float f; unsigned u; } v; v.f = f;
    unsigned r = (v.u + 0x7FFFu + ((v.u >> 16) & 1u)) >> 16;
    return (u16)r;
}
__device__ inline float bf2f(u16 b) {
    union { unsigned u; float f; } v; v.u = ((unsigned)b) << 16;
    return v.f;
}
__device__ inline unsigned pack2(float a, float b) {
    return (unsigned)f2bf(a) | ((unsigned)f2bf(b) << 16);
}

#define GLDS16(gp, lp)                                                         \
    __builtin_amdgcn_global_load_lds(                                          \
        (const __attribute__((address_space(1))) void*)(gp),                   \
        (__attribute__((address_space(3))) void*)(lp), 16, 0, 0)

// ---------------- CSR build ----------------
__global__ void k_count(const int* __restrict__ dst, int* __restrict__ deg, int E) {
    int e = blockIdx.x * blockDim.x + threadIdx.x;
    if (e < E) atomicAdd(&deg[dst[e]], 1);
}

__global__ void k_scan_block(const int* __restrict__ deg, int* __restrict__ off,
                             int* __restrict__ bsum, int n) {
    __shared__ int s[256];
    int t = threadIdx.x;
    int base = blockIdx.x * 1024 + t * 4;
    int v[4];
#pragma unroll
    for (int i = 0; i < 4; i++) v[i] = (base + i < n) ? deg[base + i] : 0;
    int sum = v[0] + v[1] + v[2] + v[3];
    int val = sum;
    s[t] = val;
    __syncthreads();
    for (int o = 1; o < 256; o <<= 1) {
        int x = (t >= o) ? s[t - o] : 0;
        __syncthreads();
        val += x;
        s[t] = val;
        __syncthreads();
    }
    int run = val - sum;
#pragma unroll
    for (int i = 0; i < 4; i++) {
        if (base + i < n) off[base + i] = run;
        run += v[i];
    }
    if (t == 255) bsum[blockIdx.x] = val;
}

__global__ void k_scan_bsum(int* __restrict__ bsum, int nb) {
    if (threadIdx.x == 0 && blockIdx.x == 0) {
        int acc = 0;
        for (int i = 0; i < nb; i++) { int v = bsum[i]; bsum[i] = acc; acc += v; }
    }
}

__global__ void k_scan_add(int* __restrict__ off, const int* __restrict__ bsum, int n) {
    int t = threadIdx.x;
    int base = blockIdx.x * 1024 + t * 4;
    int add = bsum[blockIdx.x];
#pragma unroll
    for (int i = 0; i < 4; i++)
        if (base + i < n) off[base + i] += add;
}

__global__ void k_fill(const int* __restrict__ src, const int* __restrict__ dst,
                       const int* __restrict__ off, int* __restrict__ cur,
                       int* __restrict__ eidx, int E) {
    int e = blockIdx.x * blockDim.x + threadIdx.x;
    if (e < E) {
        int d = dst[e];
        int p = atomicAdd(&cur[d], 1);
        eidx[off[d] + p] = src[e];
    }
}

__global__ void k_invdeg(const int* __restrict__ deg, float* __restrict__ inv, int n) {
    int i = blockIdx.x * blockDim.x + threadIdx.x;
    if (i < n) { int d = deg[i]; inv[i] = 1.0f / (float)(d > 1 ? d : 1); }
}

// ---------------- precision-split prep ----------------
// x (fp32 [n][128]) -> hi/lo bf16 planes [n][128]
__global__ void k_prepX(const float* __restrict__ x, u16* __restrict__ hi,
                        u16* __restrict__ lo, int n32) {
    int i = blockIdx.x * blockDim.x + threadIdx.x;  // over n*32 float4s
    if (i >= n32) return;
    float4 v = ((const float4*)x)[i];
    float h0 = bf2f(f2bf(v.x)), h1 = bf2f(f2bf(v.y)), h2 = bf2f(f2bf(v.z)), h3 = bf2f(f2bf(v.w));
    uint2 hp, lp;
    hp.x = pack2(h0, h1); hp.y = pack2(h2, h3);
    lp.x = pack2(v.x - h0, v.y - h1); lp.y = pack2(v.z - h2, v.w - h3);
    ((uint2*)hi)[i] = hp;
    ((uint2*)lo)[i] = lp;
}

// W_self [128][fout], W_neigh [128][fout] -> Bt hi/lo [128 cols][256 k] (transposed,
// fused K: k<128 self, else neigh; cols >= fout zero-padded)
__global__ void k_prepW(const float* __restrict__ Ws, const float* __restrict__ Wn,
                        u16* __restrict__ Bthi, u16* __restrict__ Btlo, int fout) {
    int idx = blockIdx.x * blockDim.x + threadIdx.x;  // 128*256
    if (idx >= 128 * 256) return;
    int col = idx >> 8;
    int k = idx & 255;
    float v = 0.f;
    if (col < fout) v = (k < 128) ? Ws[k * fout + col] : Wn[(k - 128) * fout + col];
    u16 h = f2bf(v);
    Bthi[idx] = h;
    Btlo[idx] = f2bf(v - bf2f(h));
}

// ---------------- aggregation ----------------
// one wave per node; lane handles 2 consecutive floats; emits bf16 hi/lo planes
__global__ void k_aggregate(const float* __restrict__ h_in, const int* __restrict__ eidx,
                            const int* __restrict__ off, const int* __restrict__ deg,
                            const float* __restrict__ inv, u16* __restrict__ mhi,
                            u16* __restrict__ mlo, int n) {
    int node = blockIdx.x * 4 + (threadIdx.x >> 6);
    int lane = threadIdx.x & 63;
    if (node >= n) return;
    int cnt = deg[node];
    int base = off[node];
    float2 acc = make_float2(0.f, 0.f);
    const float2* h2 = (const float2*)h_in;
    for (int j = 0; j < cnt; j++) {
        int s = eidx[base + j];
        float2 v = h2[(size_t)s * 64 + lane];
        acc.x += v.x;
        acc.y += v.y;
    }
    float iv = inv[node];
    float a0 = acc.x * iv, a1 = acc.y * iv;
    float h0 = bf2f(f2bf(a0)), h1 = bf2f(f2bf(a1));
    ((unsigned*)mhi)[(size_t)node * 64 + lane] = pack2(a0, a1);  // hi via pack2 rounds same way
    ((unsigned*)mlo)[(size_t)node * 64 + lane] = pack2(a0 - h0, a1 - h1);
}

// ---------------- MFMA GEMM (bf16x3 split) ----------------
// C[row][col] = sum_k (Ahi+Alo)[row][k] * (Bhi+Blo)[k][col] + bias, K=256 fused:
// k<128 from self planes, k>=128 from neigh planes. Tile 64 rows x 128 cols,
// 4 waves in 2x2 grid (wave: 32 rows x 64 cols = 2x4 frags of 16x16).
__global__ __launch_bounds__(256) void k_gemm_mfma(
    const u16* __restrict__ Ahi_s, const u16* __restrict__ Alo_s,
    const u16* __restrict__ Ahi_n, const u16* __restrict__ Alo_n,
    const u16* __restrict__ Bthi, const u16* __restrict__ Btlo,
    const float* __restrict__ bias, float* __restrict__ out_f32,
    u16* __restrict__ out_hi, u16* __restrict__ out_lo, int n, int fout, int relu) {
    __shared__ u16 sAhi[64 * 32];
    __shared__ u16 sAlo[64 * 32];
    __shared__ u16 sBhi[128 * 32];
    __shared__ u16 sBlo[128 * 32];

    int t = threadIdx.x;
    int w = t >> 6;
    int lane = t & 63;
    int wr = w >> 1, wc = w & 1;
    size_t row0 = (size_t)blockIdx.x * 64;

    f32x4 acc[2][4];
#pragma unroll
    for (int r = 0; r < 2; r++)
#pragma unroll
        for (int c = 0; c < 4; c++) acc[r][c] = (f32x4){0.f, 0.f, 0.f, 0.f};

    for (int kk = 0; kk < 256; kk += 32) {
        const u16* Phi = (kk < 128) ? Ahi_s : Ahi_n;
        const u16* Plo = (kk < 128) ? Alo_s : Alo_n;
        int kc = kk & 127;
        __syncthreads();
        {
            // A: 64 rows x 32 k (bf16). wave w stages rows w*16..w*16+15 per plane.
            int r = w * 16 + (lane >> 2);
            int cb = (lane & 3) * 8;  // u16 offset
            GLDS16(Phi + (row0 + r) * 128 + kc + cb, &sAhi[r * 32 + cb]);
            GLDS16(Plo + (row0 + r) * 128 + kc + cb, &sAlo[r * 32 + cb]);
        }
#pragma unroll
        for (int i = 0; i < 2; i++) {
            // B: 128 cols x 32 k. wave w stages cols w*32..w*32+31 per plane.
            int c = w * 32 + i * 16 + (lane >> 2);
            int cb = (lane & 3) * 8;
            GLDS16(Bthi + (size_t)c * 256 + kk + cb, &sBhi[c * 32 + cb]);
            GLDS16(Btlo + (size_t)c * 256 + kk + cb, &sBlo[c * 32 + cb]);
        }
        __syncthreads();

        bf16x8 a_hi[2], a_lo[2], b_hi[4], b_lo[4];
        int q8 = (lane >> 4) * 8;
#pragma unroll
        for (int r = 0; r < 2; r++) {
            int ad = (wr * 32 + r * 16 + (lane & 15)) * 32 + q8;
            a_hi[r] = *(const bf16x8*)&sAhi[ad];
            a_lo[r] = *(const bf16x8*)&sAlo[ad];
        }
#pragma unroll
        for (int c = 0; c < 4; c++) {
            int ad = (wc * 64 + c * 16 + (lane & 15)) * 32 + q8;
            b_hi[c] = *(const bf16x8*)&sBhi[ad];
            b_lo[c] = *(const bf16x8*)&sBlo[ad];
        }
#pragma unroll
        for (int r = 0; r < 2; r++)
#pragma unroll
            for (int c = 0; c < 4; c++) {
                acc[r][c] = __builtin_amdgcn_mfma_f32_16x16x32_bf16(
                    a_hi[r], b_hi[c], acc[r][c], 0, 0, 0);
                acc[r][c] = __builtin_amdgcn_mfma_f32_16x16x32_bf16(
                    a_hi[r], b_lo[c], acc[r][c], 0, 0, 0);
                acc[r][c] = __builtin_amdgcn_mfma_f32_16x16x32_bf16(
                    a_lo[r], b_hi[c], acc[r][c], 0, 0, 0);
            }
    }

    // epilogue: C/D layout col=lane&15, row=quad*4+reg
    int quad = lane >> 4;
    int lcol = lane & 15;
#pragma unroll
    for (int r = 0; r < 2; r++) {
#pragma unroll
        for (int c = 0; c < 4; c++) {
            int col = wc * 64 + c * 16 + lcol;
            float bv = (col < fout) ? bias[col] : 0.f;
#pragma unroll
            for (int g = 0; g < 4; g++) {
                size_t row = row0 + wr * 32 + r * 16 + quad * 4 + g;
                if (row >= (size_t)n || col >= fout) continue;
                float v = acc[r][c][g] + bv;
                if (relu) v = v > 0.f ? v : 0.f;
                out_f32[row * fout + col] = v;
                if (out_hi) {
                    u16 h = f2bf(v);
                    out_hi[row * 128 + col] = h;
                    out_lo[row * 128 + col] = f2bf(v - bf2f(h));
                }
            }
        }
    }
}

extern "C" void kernel_launch(void* const* d_in, const int* in_sizes, int n_in,
                              void* d_out, int out_size, void* d_ws, size_t ws_size,
                              hipStream_t stream) {
    const float* x = (const float*)d_in[0];
    const int* src = (const int*)d_in[1];
    const int* dst = (const int*)d_in[2];
    const float* Ws0 = (const float*)d_in[3];
    const float* Wn0 = (const float*)d_in[4];
    const float* b0 = (const float*)d_in[5];
    const float* Ws1 = (const float*)d_in[6];
    const float* Wn1 = (const float*)d_in[7];
    const float* b1 = (const float*)d_in[8];
    const float* Ws2 = (const float*)d_in[9];
    const float* Wn2 = (const float*)d_in[10];
    const float* b2 = (const float*)d_in[11];
    float* out = (float*)d_out;

    const int N = in_sizes[0] / 128;
    const int E = in_sizes[1];
    const int Npad = ((N + 63) / 64) * 64;  // GLDS may read pad rows (poison, finite)

    // ---- workspace layout (bytes) ----
    char* p = (char*)d_ws;
    float* hbuf = (float*)p; p += (size_t)Npad * 128 * 4;       // fp32 h (reused L0->L1)
    u16* P0hi = (u16*)p; p += (size_t)Npad * 128 * 2;           // x planes, then h1 planes
    u16* P0lo = (u16*)p; p += (size_t)Npad * 128 * 2;
    u16* P1hi = (u16*)p; p += (size_t)Npad * 128 * 2;           // h0 planes
    u16* P1lo = (u16*)p; p += (size_t)Npad * 128 * 2;
    u16* Mhi = (u16*)p; p += (size_t)Npad * 128 * 2;            // msum planes
    u16* Mlo = (u16*)p; p += (size_t)Npad * 128 * 2;
    u16* Bt0h = (u16*)p; p += 128 * 256 * 2;
    u16* Bt0l = (u16*)p; p += 128 * 256 * 2;
    u16* Bt1h = (u16*)p; p += 128 * 256 * 2;
    u16* Bt1l = (u16*)p; p += 128 * 256 * 2;
    u16* Bt2h = (u16*)p; p += 128 * 256 * 2;
    u16* Bt2l = (u16*)p; p += 128 * 256 * 2;
    float* inv = (float*)p; p += (size_t)N * 4;
    int* deg = (int*)p; p += (size_t)N * 4;
    int* off = (int*)p; p += (size_t)N * 4;
    int* cur = (int*)p; p += (size_t)N * 4;
    int* eidx = (int*)p; p += (size_t)E * 4;
    int* bsum = (int*)p;

    const int nbE = (E + THREADS - 1) / THREADS;
    const int nbScan = (N + 1023) / 1024;
    const int nbN = (N + THREADS - 1) / THREADS;
    const int nbAgg = (N + 3) / 4;
    const int nbGemm = (N + 63) / 64;
    const int nbPX = (N * 32 + THREADS - 1) / THREADS;
    const int nbPW = (128 * 256 + THREADS - 1) / THREADS;

    hipMemsetAsync(deg, 0, (size_t)N * sizeof(int), stream);
    hipMemsetAsync(cur, 0, (size_t)N * sizeof(int), stream);

    k_count<<<nbE, THREADS, 0, stream>>>(dst, deg, E);
    k_scan_block<<<nbScan, 256, 0, stream>>>(deg, off, bsum, N);
    k_scan_bsum<<<1, 64, 0, stream>>>(bsum, nbScan);
    k_scan_add<<<nbScan, 256, 0, stream>>>(off, bsum, N);
    k_fill<<<nbE, THREADS, 0, stream>>>(src, dst, off, cur, eidx, E);
    k_invdeg<<<nbN, THREADS, 0, stream>>>(deg, inv, N);

    k_prepX<<<nbPX, THREADS, 0, stream>>>(x, P0hi, P0lo, N * 32);
    k_prepW<<<nbPW, THREADS, 0, stream>>>(Ws0, Wn0, Bt0h, Bt0l, 128);
    k_prepW<<<nbPW, THREADS, 0, stream>>>(Ws1, Wn1, Bt1h, Bt1l, 128);
    k_prepW<<<nbPW, THREADS, 0, stream>>>(Ws2, Wn2, Bt2h, Bt2l, 47);

    // layer 0: x -> hbuf (+P1 planes)
    k_aggregate<<<nbAgg, 256, 0, stream>>>(x, eidx, off, deg, inv, Mhi, Mlo, N);
    k_gemm_mfma<<<nbGemm, 256, 0, stream>>>(P0hi, P0lo, Mhi, Mlo, Bt0h, Bt0l, b0,
                                            hbuf, P1hi, P1lo, N, 128, 1);
    // layer 1: hbuf -> hbuf (+P0 planes)
    k_aggregate<<<nbAgg, 256, 0, stream>>>(hbuf, eidx, off, deg, inv, Mhi, Mlo, N);
    k_gemm_mfma<<<nbGemm, 256, 0, stream>>>(P1hi, P1lo, Mhi, Mlo, Bt1h, Bt1l, b1,
                                            hbuf, P0hi, P0lo, N, 128, 1);
    // layer 2: hbuf -> out (C=47, no relu, no planes)
    k_aggregate<<<nbAgg, 256, 0, stream>>>(hbuf, eidx, off, deg, inv, Mhi, Mlo, N);
    k_gemm_mfma<<<nbGemm, 256, 0, stream>>>(P0hi, P0lo, Mhi, Mlo, Bt2h, Bt2l, b2,
                                            out, (u16*)nullptr, (u16*)nullptr, N, 47, 0);
}

// Round 3
// 383.380 us; speedup vs baseline: 1.5396x; 1.2043x over previous
//
#include <hip/hip_runtime.h>
#include <hip/hip_bf16.h>

// GraphSAGE 3-layer forward.
// CSR build (int) -> per layer: aggregate (fp32 gather-mean, 8-deep MLP,
// emits bf16 hi/lo planes) -> MFMA GEMM (bf16x3 split == fp32-quality)
// fused self+neigh (K=256).

#define THREADS 256

typedef unsigned short u16;
typedef __attribute__((ext_vector_type(8))) short bf16x8;
typedef __attribute__((ext_vector_type(4))) float f32x4;

__device__ inline u16 f2bf(float f) {
    union { float f; unsigned u; } v; v.f = f;
    unsigned r = (v.u + 0x7FFFu + ((v.u >> 16) & 1u)) >> 16;
    return (u16)r;
}
__device__ inline float bf2f(u16 b) {
    union { unsigned u; float f; } v; v.u = ((unsigned)b) << 16;
    return v.f;
}
__device__ inline unsigned pack2(float a, float b) {
    return (unsigned)f2bf(a) | ((unsigned)f2bf(b) << 16);
}

#define GLDS16(gp, lp)                                                         \
    __builtin_amdgcn_global_load_lds(                                          \
        (const __attribute__((address_space(1))) void*)(gp),                   \
        (__attribute__((address_space(3))) void*)(lp), 16, 0, 0)

// ---------------- CSR build ----------------
__global__ void k_count(const int* __restrict__ dst, int* __restrict__ deg, int E) {
    int e = blockIdx.x * blockDim.x + threadIdx.x;
    if (e < E) atomicAdd(&deg[dst[e]], 1);
}

__global__ void k_scan_block(const int* __restrict__ deg, int* __restrict__ off,
                             int* __restrict__ bsum, int n) {
    __shared__ int s[256];
    int t = threadIdx.x;
    int base = blockIdx.x * 1024 + t * 4;
    int v[4];
#pragma unroll
    for (int i = 0; i < 4; i++) v[i] = (base + i < n) ? deg[base + i] : 0;
    int sum = v[0] + v[1] + v[2] + v[3];
    int val = sum;
    s[t] = val;
    __syncthreads();
    for (int o = 1; o < 256; o <<= 1) {
        int x = (t >= o) ? s[t - o] : 0;
        __syncthreads();
        val += x;
        s[t] = val;
        __syncthreads();
    }
    int run = val - sum;
#pragma unroll
    for (int i = 0; i < 4; i++) {
        if (base + i < n) off[base + i] = run;
        run += v[i];
    }
    if (t == 255) bsum[blockIdx.x] = val;
}

__global__ void k_scan_bsum(int* __restrict__ bsum, int nb) {
    if (threadIdx.x == 0 && blockIdx.x == 0) {
        int acc = 0;
        for (int i = 0; i < nb; i++) { int v = bsum[i]; bsum[i] = acc; acc += v; }
    }
}

__global__ void k_scan_add(int* __restrict__ off, const int* __restrict__ bsum, int n) {
    int t = threadIdx.x;
    int base = blockIdx.x * 1024 + t * 4;
    int add = bsum[blockIdx.x];
#pragma unroll
    for (int i = 0; i < 4; i++)
        if (base + i < n) off[base + i] += add;
}

__global__ void k_fill(const int* __restrict__ src, const int* __restrict__ dst,
                       const int* __restrict__ off, int* __restrict__ cur,
                       int* __restrict__ eidx, int E) {
    int e = blockIdx.x * blockDim.x + threadIdx.x;
    if (e < E) {
        int d = dst[e];
        int p = atomicAdd(&cur[d], 1);
        eidx[off[d] + p] = src[e];
    }
}

// ---------------- precision-split prep ----------------
__global__ void k_prepX(const float* __restrict__ x, u16* __restrict__ hi,
                        u16* __restrict__ lo, int n32) {
    int i = blockIdx.x * blockDim.x + threadIdx.x;  // over n*32 float4s
    if (i >= n32) return;
    float4 v = ((const float4*)x)[i];
    float h0 = bf2f(f2bf(v.x)), h1 = bf2f(f2bf(v.y)), h2 = bf2f(f2bf(v.z)), h3 = bf2f(f2bf(v.w));
    uint2 hp, lp;
    hp.x = pack2(h0, h1); hp.y = pack2(h2, h3);
    lp.x = pack2(v.x - h0, v.y - h1); lp.y = pack2(v.z - h2, v.w - h3);
    ((uint2*)hi)[i] = hp;
    ((uint2*)lo)[i] = lp;
}

// W_self [128][fout], W_neigh [128][fout] -> Bt hi/lo [128 cols][256 k]
__global__ void k_prepW(const float* __restrict__ Ws, const float* __restrict__ Wn,
                        u16* __restrict__ Bthi, u16* __restrict__ Btlo, int fout) {
    int idx = blockIdx.x * blockDim.x + threadIdx.x;  // 128*256
    if (idx >= 128 * 256) return;
    int col = idx >> 8;
    int k = idx & 255;
    float v = 0.f;
    if (col < fout) v = (k < 128) ? Ws[k * fout + col] : Wn[(k - 128) * fout + col];
    u16 h = f2bf(v);
    Bthi[idx] = h;
    Btlo[idx] = f2bf(v - bf2f(h));
}

// ---------------- aggregation ----------------
// one wave per node; lane handles 2 consecutive floats; masked 8-edge chunks
// keep 8 independent 512B row-gathers in flight (latency hiding).
__global__ void k_aggregate(const float* __restrict__ h_in, const int* __restrict__ eidx,
                            const int* __restrict__ off, const int* __restrict__ deg,
                            u16* __restrict__ mhi, u16* __restrict__ mlo, int n) {
    int node = blockIdx.x * 4 + (threadIdx.x >> 6);
    int lane = threadIdx.x & 63;
    if (node >= n) return;
    int cnt = deg[node];
    int base = off[node];
    const float2* h2 = (const float2*)h_in;
    float2 acc = make_float2(0.f, 0.f);
    for (int j = 0; j < cnt; j += 8) {
        int s[8];
        float m[8];
#pragma unroll
        for (int u = 0; u < 8; u++) {
            int jj = j + u;
            s[u] = eidx[base + (jj < cnt ? jj : 0)];
            m[u] = (jj < cnt) ? 1.f : 0.f;
        }
        float2 v[8];
#pragma unroll
        for (int u = 0; u < 8; u++) v[u] = h2[(size_t)s[u] * 64 + lane];
#pragma unroll
        for (int u = 0; u < 8; u++) {
            acc.x = fmaf(m[u], v[u].x, acc.x);
            acc.y = fmaf(m[u], v[u].y, acc.y);
        }
    }
    float iv = 1.0f / (float)(cnt > 1 ? cnt : 1);
    float a0 = acc.x * iv, a1 = acc.y * iv;
    float h0 = bf2f(f2bf(a0)), h1 = bf2f(f2bf(a1));
    ((unsigned*)mhi)[(size_t)node * 64 + lane] = pack2(a0, a1);
    ((unsigned*)mlo)[(size_t)node * 64 + lane] = pack2(a0 - h0, a1 - h1);
}

// ---------------- MFMA GEMM (bf16x3 split) ----------------
__global__ __launch_bounds__(256) void k_gemm_mfma(
    const u16* __restrict__ Ahi_s, const u16* __restrict__ Alo_s,
    const u16* __restrict__ Ahi_n, const u16* __restrict__ Alo_n,
    const u16* __restrict__ Bthi, const u16* __restrict__ Btlo,
    const float* __restrict__ bias, float* __restrict__ out_f32,
    u16* __restrict__ out_hi, u16* __restrict__ out_lo, int n, int fout, int relu) {
    __shared__ u16 sAhi[64 * 32];
    __shared__ u16 sAlo[64 * 32];
    __shared__ u16 sBhi[128 * 32];
    __shared__ u16 sBlo[128 * 32];

    int t = threadIdx.x;
    int w = t >> 6;
    int lane = t & 63;
    int wr = w >> 1, wc = w & 1;
    size_t row0 = (size_t)blockIdx.x * 64;

    f32x4 acc[2][4];
#pragma unroll
    for (int r = 0; r < 2; r++)
#pragma unroll
        for (int c = 0; c < 4; c++) acc[r][c] = (f32x4){0.f, 0.f, 0.f, 0.f};

    for (int kk = 0; kk < 256; kk += 32) {
        const u16* Phi = (kk < 128) ? Ahi_s : Ahi_n;
        const u16* Plo = (kk < 128) ? Alo_s : Alo_n;
        int kc = kk & 127;
        __syncthreads();
        {
            int r = w * 16 + (lane >> 2);
            int cb = (lane & 3) * 8;
            GLDS16(Phi + (row0 + r) * 128 + kc + cb, &sAhi[r * 32 + cb]);
            GLDS16(Plo + (row0 + r) * 128 + kc + cb, &sAlo[r * 32 + cb]);
        }
#pragma unroll
        for (int i = 0; i < 2; i++) {
            int c = w * 32 + i * 16 + (lane >> 2);
            int cb = (lane & 3) * 8;
            GLDS16(Bthi + (size_t)c * 256 + kk + cb, &sBhi[c * 32 + cb]);
            GLDS16(Btlo + (size_t)c * 256 + kk + cb, &sBlo[c * 32 + cb]);
        }
        __syncthreads();

        bf16x8 a_hi[2], a_lo[2], b_hi[4], b_lo[4];
        int q8 = (lane >> 4) * 8;
#pragma unroll
        for (int r = 0; r < 2; r++) {
            int ad = (wr * 32 + r * 16 + (lane & 15)) * 32 + q8;
            a_hi[r] = *(const bf16x8*)&sAhi[ad];
            a_lo[r] = *(const bf16x8*)&sAlo[ad];
        }
#pragma unroll
        for (int c = 0; c < 4; c++) {
            int ad = (wc * 64 + c * 16 + (lane & 15)) * 32 + q8;
            b_hi[c] = *(const bf16x8*)&sBhi[ad];
            b_lo[c] = *(const bf16x8*)&sBlo[ad];
        }
#pragma unroll
        for (int r = 0; r < 2; r++)
#pragma unroll
            for (int c = 0; c < 4; c++) {
                acc[r][c] = __builtin_amdgcn_mfma_f32_16x16x32_bf16(
                    a_hi[r], b_hi[c], acc[r][c], 0, 0, 0);
                acc[r][c] = __builtin_amdgcn_mfma_f32_16x16x32_bf16(
                    a_hi[r], b_lo[c], acc[r][c], 0, 0, 0);
                acc[r][c] = __builtin_amdgcn_mfma_f32_16x16x32_bf16(
                    a_lo[r], b_hi[c], acc[r][c], 0, 0, 0);
            }
    }

    // epilogue: C/D layout col=lane&15, row=quad*4+reg
    int quad = lane >> 4;
    int lcol = lane & 15;
#pragma unroll
    for (int r = 0; r < 2; r++) {
#pragma unroll
        for (int c = 0; c < 4; c++) {
            int col = wc * 64 + c * 16 + lcol;
            float bv = (col < fout) ? bias[col] : 0.f;
#pragma unroll
            for (int g = 0; g < 4; g++) {
                size_t row = row0 + wr * 32 + r * 16 + quad * 4 + g;
                if (row >= (size_t)n || col >= fout) continue;
                float v = acc[r][c][g] + bv;
                if (relu) v = v > 0.f ? v : 0.f;
                out_f32[row * fout + col] = v;
                if (out_hi) {
                    u16 h = f2bf(v);
                    out_hi[row * 128 + col] = h;
                    out_lo[row * 128 + col] = f2bf(v - bf2f(h));
                }
            }
        }
    }
}

extern "C" void kernel_launch(void* const* d_in, const int* in_sizes, int n_in,
                              void* d_out, int out_size, void* d_ws, size_t ws_size,
                              hipStream_t stream) {
    const float* x = (const float*)d_in[0];
    const int* src = (const int*)d_in[1];
    const int* dst = (const int*)d_in[2];
    const float* Ws0 = (const float*)d_in[3];
    const float* Wn0 = (const float*)d_in[4];
    const float* b0 = (const float*)d_in[5];
    const float* Ws1 = (const float*)d_in[6];
    const float* Wn1 = (const float*)d_in[7];
    const float* b1 = (const float*)d_in[8];
    const float* Ws2 = (const float*)d_in[9];
    const float* Wn2 = (const float*)d_in[10];
    const float* b2 = (const float*)d_in[11];
    float* out = (float*)d_out;

    const int N = in_sizes[0] / 128;
    const int E = in_sizes[1];
    const int Npad = ((N + 63) / 64) * 64;

    // ---- workspace layout (bytes) ----
    char* p = (char*)d_ws;
    float* hbuf = (float*)p; p += (size_t)Npad * 128 * 4;
    u16* P0hi = (u16*)p; p += (size_t)Npad * 128 * 2;
    u16* P0lo = (u16*)p; p += (size_t)Npad * 128 * 2;
    u16* P1hi = (u16*)p; p += (size_t)Npad * 128 * 2;
    u16* P1lo = (u16*)p; p += (size_t)Npad * 128 * 2;
    u16* Mhi = (u16*)p; p += (size_t)Npad * 128 * 2;
    u16* Mlo = (u16*)p; p += (size_t)Npad * 128 * 2;
    u16* Bt0h = (u16*)p; p += 128 * 256 * 2;
    u16* Bt0l = (u16*)p; p += 128 * 256 * 2;
    u16* Bt1h = (u16*)p; p += 128 * 256 * 2;
    u16* Bt1l = (u16*)p; p += 128 * 256 * 2;
    u16* Bt2h = (u16*)p; p += 128 * 256 * 2;
    u16* Bt2l = (u16*)p; p += 128 * 256 * 2;
    int* deg = (int*)p; p += (size_t)N * 4;
    int* off = (int*)p; p += (size_t)N * 4;
    int* cur = (int*)p; p += (size_t)N * 4;
    int* eidx = (int*)p; p += (size_t)E * 4;
    int* bsum = (int*)p;

    const int nbE = (E + THREADS - 1) / THREADS;
    const int nbScan = (N + 1023) / 1024;
    const int nbAgg = (N + 3) / 4;
    const int nbGemm = (N + 63) / 64;
    const int nbPX = (N * 32 + THREADS - 1) / THREADS;
    const int nbPW = (128 * 256 + THREADS - 1) / THREADS;

    hipMemsetAsync(deg, 0, (size_t)N * sizeof(int), stream);
    hipMemsetAsync(cur, 0, (size_t)N * sizeof(int), stream);

    k_count<<<nbE, THREADS, 0, stream>>>(dst, deg, E);
    k_scan_block<<<nbScan, 256, 0, stream>>>(deg, off, bsum, N);
    k_scan_bsum<<<1, 64, 0, stream>>>(bsum, nbScan);
    k_scan_add<<<nbScan, 256, 0, stream>>>(off, bsum, N);
    k_fill<<<nbE, THREADS, 0, stream>>>(src, dst, off, cur, eidx, E);

    k_prepX<<<nbPX, THREADS, 0, stream>>>(x, P0hi, P0lo, N * 32);
    k_prepW<<<nbPW, THREADS, 0, stream>>>(Ws0, Wn0, Bt0h, Bt0l, 128);
    k_prepW<<<nbPW, THREADS, 0, stream>>>(Ws1, Wn1, Bt1h, Bt1l, 128);
    k_prepW<<<nbPW, THREADS, 0, stream>>>(Ws2, Wn2, Bt2h, Bt2l, 47);

    // layer 0: x -> hbuf (+P1 planes)
    k_aggregate<<<nbAgg, 256, 0, stream>>>(x, eidx, off, deg, Mhi, Mlo, N);
    k_gemm_mfma<<<nbGemm, 256, 0, stream>>>(P0hi, P0lo, Mhi, Mlo, Bt0h, Bt0l, b0,
                                            hbuf, P1hi, P1lo, N, 128, 1);
    // layer 1: hbuf -> hbuf (+P0 planes)
    k_aggregate<<<nbAgg, 256, 0, stream>>>(hbuf, eidx, off, deg, Mhi, Mlo, N);
    k_gemm_mfma<<<nbGemm, 256, 0, stream>>>(P1hi, P1lo, Mhi, Mlo, Bt1h, Bt1l, b1,
                                            hbuf, P0hi, P0lo, N, 128, 1);
    // layer 2: hbuf -> out (C=47, no relu, no planes)
    k_aggregate<<<nbAgg, 256, 0, stream>>>(hbuf, eidx, off, deg, Mhi, Mlo, N);
    k_gemm_mfma<<<nbGemm, 256, 0, stream>>>(P0hi, P0lo, Mhi, Mlo, Bt2h, Bt2l, b2,
                                            out, (u16*)nullptr, (u16*)nullptr, N, 47, 0);
}

// Round 4
// 325.460 us; speedup vs baseline: 1.8136x; 1.1780x over previous
//
#include <hip/hip_runtime.h>
#include <hip/hip_bf16.h>

// GraphSAGE 3-layer forward.
// CSR build (int) -> prep bf16 hi/lo planes -> per layer:
//   aggregate: gather bf16 HI-plane rows (256B/row), fp32 mean, emit hi/lo planes
//   GEMM: MFMA bf16x3 split (fp32-quality), fused self+neigh (K=256),
//         epilogue writes next layer's hi/lo planes (no fp32 h buffer).

#define THREADS 256

typedef unsigned short u16;
typedef __attribute__((ext_vector_type(8))) short bf16x8;
typedef __attribute__((ext_vector_type(4))) float f32x4;

__device__ inline u16 f2bf(float f) {
    union { float f; unsigned u; } v; v.f = f;
    unsigned r = (v.u + 0x7FFFu + ((v.u >> 16) & 1u)) >> 16;
    return (u16)r;
}
__device__ inline float bf2f(u16 b) {
    union { unsigned u; float f; } v; v.u = ((unsigned)b) << 16;
    return v.f;
}
__device__ inline unsigned pack2(float a, float b) {
    return (unsigned)f2bf(a) | ((unsigned)f2bf(b) << 16);
}

#define GLDS16(gp, lp)                                                         \
    __builtin_amdgcn_global_load_lds(                                          \
        (const __attribute__((address_space(1))) void*)(gp),                   \
        (__attribute__((address_space(3))) void*)(lp), 16, 0, 0)

// ---------------- CSR build ----------------
__global__ void k_count(const int* __restrict__ dst, int* __restrict__ deg, int E) {
    int e = blockIdx.x * blockDim.x + threadIdx.x;
    if (e < E) atomicAdd(&deg[dst[e]], 1);
}

__global__ void k_scan_block(const int* __restrict__ deg, int* __restrict__ off,
                             int* __restrict__ bsum, int n) {
    __shared__ int s[256];
    int t = threadIdx.x;
    int base = blockIdx.x * 1024 + t * 4;
    int v[4];
#pragma unroll
    for (int i = 0; i < 4; i++) v[i] = (base + i < n) ? deg[base + i] : 0;
    int sum = v[0] + v[1] + v[2] + v[3];
    int val = sum;
    s[t] = val;
    __syncthreads();
    for (int o = 1; o < 256; o <<= 1) {
        int x = (t >= o) ? s[t - o] : 0;
        __syncthreads();
        val += x;
        s[t] = val;
        __syncthreads();
    }
    int run = val - sum;
#pragma unroll
    for (int i = 0; i < 4; i++) {
        if (base + i < n) off[base + i] = run;
        run += v[i];
    }
    if (t == 255) bsum[blockIdx.x] = val;
}

__global__ void k_scan_bsum(int* __restrict__ bsum, int nb) {
    if (threadIdx.x == 0 && blockIdx.x == 0) {
        int acc = 0;
        for (int i = 0; i < nb; i++) { int v = bsum[i]; bsum[i] = acc; acc += v; }
    }
}

__global__ void k_scan_add(int* __restrict__ off, const int* __restrict__ bsum, int n) {
    int t = threadIdx.x;
    int base = blockIdx.x * 1024 + t * 4;
    int add = bsum[blockIdx.x];
#pragma unroll
    for (int i = 0; i < 4; i++)
        if (base + i < n) off[base + i] += add;
}

__global__ void k_fill(const int* __restrict__ src, const int* __restrict__ dst,
                       const int* __restrict__ off, int* __restrict__ cur,
                       int* __restrict__ eidx, int E) {
    int e = blockIdx.x * blockDim.x + threadIdx.x;
    if (e < E) {
        int d = dst[e];
        int p = atomicAdd(&cur[d], 1);
        eidx[off[d] + p] = src[e];
    }
}

// ---------------- precision-split prep ----------------
__global__ void k_prepX(const float* __restrict__ x, u16* __restrict__ hi,
                        u16* __restrict__ lo, int n32) {
    int i = blockIdx.x * blockDim.x + threadIdx.x;  // over n*32 float4s
    if (i >= n32) return;
    float4 v = ((const float4*)x)[i];
    float h0 = bf2f(f2bf(v.x)), h1 = bf2f(f2bf(v.y)), h2 = bf2f(f2bf(v.z)), h3 = bf2f(f2bf(v.w));
    uint2 hp, lp;
    hp.x = pack2(h0, h1); hp.y = pack2(h2, h3);
    lp.x = pack2(v.x - h0, v.y - h1); lp.y = pack2(v.z - h2, v.w - h3);
    ((uint2*)hi)[i] = hp;
    ((uint2*)lo)[i] = lp;
}

// W_self [128][fout], W_neigh [128][fout] -> Bt hi/lo [128 cols][256 k]
__global__ void k_prepW(const float* __restrict__ Ws, const float* __restrict__ Wn,
                        u16* __restrict__ Bthi, u16* __restrict__ Btlo, int fout) {
    int idx = blockIdx.x * blockDim.x + threadIdx.x;  // 128*256
    if (idx >= 128 * 256) return;
    int col = idx >> 8;
    int k = idx & 255;
    float v = 0.f;
    if (col < fout) v = (k < 128) ? Ws[k * fout + col] : Wn[(k - 128) * fout + col];
    u16 h = f2bf(v);
    Bthi[idx] = h;
    Btlo[idx] = f2bf(v - bf2f(h));
}

// ---------------- aggregation ----------------
// one wave per node; gathers bf16 HI-plane rows (256B/row, lane loads 4B = 2 feats);
// masked 8-edge chunks keep 8 independent gathers in flight; fp32 accumulate.
__global__ void k_aggregate(const u16* __restrict__ hi_in, const int* __restrict__ eidx,
                            const int* __restrict__ off, const int* __restrict__ deg,
                            u16* __restrict__ mhi, u16* __restrict__ mlo, int n) {
    int node = blockIdx.x * 4 + (threadIdx.x >> 6);
    int lane = threadIdx.x & 63;
    if (node >= n) return;
    int cnt = deg[node];
    int base = off[node];
    const unsigned* h1 = (const unsigned*)hi_in;  // 2 bf16 feats per word
    float2 acc = make_float2(0.f, 0.f);
    for (int j = 0; j < cnt; j += 8) {
        int s[8];
        float m[8];
#pragma unroll
        for (int u = 0; u < 8; u++) {
            int jj = j + u;
            s[u] = eidx[base + (jj < cnt ? jj : 0)];
            m[u] = (jj < cnt) ? 1.f : 0.f;
        }
        unsigned v[8];
#pragma unroll
        for (int u = 0; u < 8; u++) v[u] = h1[(size_t)s[u] * 64 + lane];
#pragma unroll
        for (int u = 0; u < 8; u++) {
            acc.x = fmaf(m[u], bf2f((u16)(v[u] & 0xffffu)), acc.x);
            acc.y = fmaf(m[u], bf2f((u16)(v[u] >> 16)), acc.y);
        }
    }
    float iv = 1.0f / (float)(cnt > 1 ? cnt : 1);
    float a0 = acc.x * iv, a1 = acc.y * iv;
    float h0 = bf2f(f2bf(a0)), h1v = bf2f(f2bf(a1));
    ((unsigned*)mhi)[(size_t)node * 64 + lane] = pack2(a0, a1);
    ((unsigned*)mlo)[(size_t)node * 64 + lane] = pack2(a0 - h0, a1 - h1v);
}

// ---------------- MFMA GEMM (bf16x3 split) ----------------
__global__ __launch_bounds__(256) void k_gemm_mfma(
    const u16* __restrict__ Ahi_s, const u16* __restrict__ Alo_s,
    const u16* __restrict__ Ahi_n, const u16* __restrict__ Alo_n,
    const u16* __restrict__ Bthi, const u16* __restrict__ Btlo,
    const float* __restrict__ bias, float* __restrict__ out_f32,
    u16* __restrict__ out_hi, u16* __restrict__ out_lo, int n, int fout, int relu) {
    __shared__ u16 sAhi[64 * 32];
    __shared__ u16 sAlo[64 * 32];
    __shared__ u16 sBhi[128 * 32];
    __shared__ u16 sBlo[128 * 32];

    int t = threadIdx.x;
    int w = t >> 6;
    int lane = t & 63;
    int wr = w >> 1, wc = w & 1;
    size_t row0 = (size_t)blockIdx.x * 64;

    f32x4 acc[2][4];
#pragma unroll
    for (int r = 0; r < 2; r++)
#pragma unroll
        for (int c = 0; c < 4; c++) acc[r][c] = (f32x4){0.f, 0.f, 0.f, 0.f};

    for (int kk = 0; kk < 256; kk += 32) {
        const u16* Phi = (kk < 128) ? Ahi_s : Ahi_n;
        const u16* Plo = (kk < 128) ? Alo_s : Alo_n;
        int kc = kk & 127;
        __syncthreads();
        {
            int r = w * 16 + (lane >> 2);
            int cb = (lane & 3) * 8;
            GLDS16(Phi + (row0 + r) * 128 + kc + cb, &sAhi[r * 32 + cb]);
            GLDS16(Plo + (row0 + r) * 128 + kc + cb, &sAlo[r * 32 + cb]);
        }
#pragma unroll
        for (int i = 0; i < 2; i++) {
            int c = w * 32 + i * 16 + (lane >> 2);
            int cb = (lane & 3) * 8;
            GLDS16(Bthi + (size_t)c * 256 + kk + cb, &sBhi[c * 32 + cb]);
            GLDS16(Btlo + (size_t)c * 256 + kk + cb, &sBlo[c * 32 + cb]);
        }
        __syncthreads();

        bf16x8 a_hi[2], a_lo[2], b_hi[4], b_lo[4];
        int q8 = (lane >> 4) * 8;
#pragma unroll
        for (int r = 0; r < 2; r++) {
            int ad = (wr * 32 + r * 16 + (lane & 15)) * 32 + q8;
            a_hi[r] = *(const bf16x8*)&sAhi[ad];
            a_lo[r] = *(const bf16x8*)&sAlo[ad];
        }
#pragma unroll
        for (int c = 0; c < 4; c++) {
            int ad = (wc * 64 + c * 16 + (lane & 15)) * 32 + q8;
            b_hi[c] = *(const bf16x8*)&sBhi[ad];
            b_lo[c] = *(const bf16x8*)&sBlo[ad];
        }
#pragma unroll
        for (int r = 0; r < 2; r++)
#pragma unroll
            for (int c = 0; c < 4; c++) {
                acc[r][c] = __builtin_amdgcn_mfma_f32_16x16x32_bf16(
                    a_hi[r], b_hi[c], acc[r][c], 0, 0, 0);
                acc[r][c] = __builtin_amdgcn_mfma_f32_16x16x32_bf16(
                    a_hi[r], b_lo[c], acc[r][c], 0, 0, 0);
                acc[r][c] = __builtin_amdgcn_mfma_f32_16x16x32_bf16(
                    a_lo[r], b_hi[c], acc[r][c], 0, 0, 0);
            }
    }

    // epilogue: C/D layout col=lane&15, row=quad*4+reg
    int quad = lane >> 4;
    int lcol = lane & 15;
#pragma unroll
    for (int r = 0; r < 2; r++) {
#pragma unroll
        for (int c = 0; c < 4; c++) {
            int col = wc * 64 + c * 16 + lcol;
            float bv = (col < fout) ? bias[col] : 0.f;
#pragma unroll
            for (int g = 0; g < 4; g++) {
                size_t row = row0 + wr * 32 + r * 16 + quad * 4 + g;
                if (row >= (size_t)n || col >= fout) continue;
                float v = acc[r][c][g] + bv;
                if (relu) v = v > 0.f ? v : 0.f;
                if (out_f32) out_f32[row * fout + col] = v;
                if (out_hi) {
                    u16 h = f2bf(v);
                    out_hi[row * 128 + col] = h;
                    out_lo[row * 128 + col] = f2bf(v - bf2f(h));
                }
            }
        }
    }
}

extern "C" void kernel_launch(void* const* d_in, const int* in_sizes, int n_in,
                              void* d_out, int out_size, void* d_ws, size_t ws_size,
                              hipStream_t stream) {
    const float* x = (const float*)d_in[0];
    const int* src = (const int*)d_in[1];
    const int* dst = (const int*)d_in[2];
    const float* Ws0 = (const float*)d_in[3];
    const float* Wn0 = (const float*)d_in[4];
    const float* b0 = (const float*)d_in[5];
    const float* Ws1 = (const float*)d_in[6];
    const float* Wn1 = (const float*)d_in[7];
    const float* b1 = (const float*)d_in[8];
    const float* Ws2 = (const float*)d_in[9];
    const float* Wn2 = (const float*)d_in[10];
    const float* b2 = (const float*)d_in[11];
    float* out = (float*)d_out;

    const int N = in_sizes[0] / 128;
    const int E = in_sizes[1];
    const int Npad = ((N + 63) / 64) * 64;

    // ---- workspace layout (bytes) ----
    char* p = (char*)d_ws;
    u16* P0hi = (u16*)p; p += (size_t)Npad * 128 * 2;  // x planes, then h1 planes
    u16* P0lo = (u16*)p; p += (size_t)Npad * 128 * 2;
    u16* P1hi = (u16*)p; p += (size_t)Npad * 128 * 2;  // h0 planes
    u16* P1lo = (u16*)p; p += (size_t)Npad * 128 * 2;
    u16* Mhi = (u16*)p; p += (size_t)Npad * 128 * 2;   // msum planes
    u16* Mlo = (u16*)p; p += (size_t)Npad * 128 * 2;
    u16* Bt0h = (u16*)p; p += 128 * 256 * 2;
    u16* Bt0l = (u16*)p; p += 128 * 256 * 2;
    u16* Bt1h = (u16*)p; p += 128 * 256 * 2;
    u16* Bt1l = (u16*)p; p += 128 * 256 * 2;
    u16* Bt2h = (u16*)p; p += 128 * 256 * 2;
    u16* Bt2l = (u16*)p; p += 128 * 256 * 2;
    int* deg = (int*)p; p += (size_t)N * 4;
    int* off = (int*)p; p += (size_t)N * 4;
    int* cur = (int*)p; p += (size_t)N * 4;
    int* eidx = (int*)p; p += (size_t)E * 4;
    int* bsum = (int*)p;

    const int nbE = (E + THREADS - 1) / THREADS;
    const int nbScan = (N + 1023) / 1024;
    const int nbAgg = (N + 3) / 4;
    const int nbGemm = (N + 63) / 64;
    const int nbPX = (N * 32 + THREADS - 1) / THREADS;
    const int nbPW = (128 * 256 + THREADS - 1) / THREADS;

    hipMemsetAsync(deg, 0, (size_t)N * sizeof(int), stream);
    hipMemsetAsync(cur, 0, (size_t)N * sizeof(int), stream);

    k_count<<<nbE, THREADS, 0, stream>>>(dst, deg, E);
    k_scan_block<<<nbScan, 256, 0, stream>>>(deg, off, bsum, N);
    k_scan_bsum<<<1, 64, 0, stream>>>(bsum, nbScan);
    k_scan_add<<<nbScan, 256, 0, stream>>>(off, bsum, N);
    k_fill<<<nbE, THREADS, 0, stream>>>(src, dst, off, cur, eidx, E);

    k_prepX<<<nbPX, THREADS, 0, stream>>>(x, P0hi, P0lo, N * 32);
    k_prepW<<<nbPW, THREADS, 0, stream>>>(Ws0, Wn0, Bt0h, Bt0l, 128);
    k_prepW<<<nbPW, THREADS, 0, stream>>>(Ws1, Wn1, Bt1h, Bt1l, 128);
    k_prepW<<<nbPW, THREADS, 0, stream>>>(Ws2, Wn2, Bt2h, Bt2l, 47);

    // layer 0: x planes -> h0 planes (P1); no fp32 h
    k_aggregate<<<nbAgg, 256, 0, stream>>>(P0hi, eidx, off, deg, Mhi, Mlo, N);
    k_gemm_mfma<<<nbGemm, 256, 0, stream>>>(P0hi, P0lo, Mhi, Mlo, Bt0h, Bt0l, b0,
                                            (float*)nullptr, P1hi, P1lo, N, 128, 1);
    // layer 1: h0 planes -> h1 planes (reuse P0)
    k_aggregate<<<nbAgg, 256, 0, stream>>>(P1hi, eidx, off, deg, Mhi, Mlo, N);
    k_gemm_mfma<<<nbGemm, 256, 0, stream>>>(P1hi, P1lo, Mhi, Mlo, Bt1h, Bt1l, b1,
                                            (float*)nullptr, P0hi, P0lo, N, 128, 1);
    // layer 2: h1 planes -> out (C=47, fp32, no relu, no planes)
    k_aggregate<<<nbAgg, 256, 0, stream>>>(P0hi, eidx, off, deg, Mhi, Mlo, N);
    k_gemm_mfma<<<nbGemm, 256, 0, stream>>>(P0hi, P0lo, Mhi, Mlo, Bt2h, Bt2l, b2,
                                            out, (u16*)nullptr, (u16*)nullptr, N, 47, 0);
}